// Round 10
// baseline (514.319 us; speedup 1.0000x reference)
//
#include <hip/hip_runtime.h>
#include <hip/hip_cooperative_groups.h>

namespace cg = cooperative_groups;

#define B_SZ   512
#define VFD    4096
#define HIDD   2048
#define EMBD   300
#define NLAB   2000
#define NPAD   320

#define G1_SPLIT 4          // gemm1 k-chunks: K=4096 -> 1024 each, 512 tiles
#define G2_SPLIT 8          // gemm2 k-chunks: K=2048 -> 256 each, 320 tiles
#define SD_SPLIT 4          // scores d-quarters (fallback grid)

typedef __attribute__((ext_vector_type(8))) short short8x;
typedef __attribute__((ext_vector_type(4))) float f32x4;
typedef __attribute__((ext_vector_type(8))) unsigned short ushort8;
typedef __attribute__((ext_vector_type(4))) unsigned short ushort4x;

typedef const __attribute__((address_space(1))) unsigned int* gas_t;
typedef __attribute__((address_space(3))) unsigned int* las_t;

__device__ inline unsigned short f2bf(float x) {
    unsigned u = __float_as_uint(x);
    u += 0x7FFF + ((u >> 16) & 1);          // round-to-nearest-even
    return (unsigned short)(u >> 16);
}

// ---------------------------------------------------------------------------
// Prep (4256 blocks):
//   [0,1024):     Xb = bf16(relu(vfs))
//   [1024,3072):  W1T[n][k] = bf16(W1[k][n])  (pair-packed transpose)
//   [3072,3232):  W2T[n][k] = bf16(W2[k][n]), n>=300 zero-padded
//   [3232,4256):  scores <- 0 (atomic accumulation target, both paths)
// ---------------------------------------------------------------------------
__global__ __launch_bounds__(256) void prep_kernel(
    const float* __restrict__ vfs, unsigned short* __restrict__ Xb,
    const float* __restrict__ W1, unsigned short* __restrict__ W1T,
    const float* __restrict__ W2, unsigned short* __restrict__ W2T,
    float* __restrict__ scores)
{
    __shared__ unsigned int Lds[64][34];
    const int tid = threadIdx.x;
    const int blk = blockIdx.x;

    if (blk < 1024) {
        const int i = (blk * 256 + tid) * 8;
        float4 a = *(const float4*)&vfs[i];
        float4 b = *(const float4*)&vfs[i + 4];
        ushort8 o;
        o[0] = f2bf(fmaxf(a.x, 0.f)); o[1] = f2bf(fmaxf(a.y, 0.f));
        o[2] = f2bf(fmaxf(a.z, 0.f)); o[3] = f2bf(fmaxf(a.w, 0.f));
        o[4] = f2bf(fmaxf(b.x, 0.f)); o[5] = f2bf(fmaxf(b.y, 0.f));
        o[6] = f2bf(fmaxf(b.z, 0.f)); o[7] = f2bf(fmaxf(b.w, 0.f));
        *(ushort8*)&Xb[i] = o;
        return;
    }
    if (blk >= 3232) {
        const int i = ((blk - 3232) * 256 + tid) * 4;
        if (i < B_SZ * NLAB) {
            float4 z = {0.f, 0.f, 0.f, 0.f};
            *(float4*)&scores[i] = z;
        }
        return;
    }

    const float* in; unsigned short* out; int N, ldK, bx, by;
    if (blk < 3072) {                       // W1: K=4096, N=2048, tiles (32,64)
        const int b = blk - 1024;
        in = W1; out = W1T; N = HIDD; ldK = VFD; bx = b & 31; by = b >> 5;
    } else {                                // W2: K=2048, N=300->320, tiles (5,32)
        const int b = blk - 3072;
        in = W2; out = W2T; N = EMBD; ldK = HIDD; bx = b % 5; by = b / 5;
    }
    const int n0 = bx * 64, k0 = by * 64;

    #pragma unroll
    for (int i = 0; i < 2; ++i) {
        const int s = tid + 256 * i;
        const int kp = s >> 4, nq = s & 15;
        const int n = n0 + nq * 4;
        float4 v0 = {0.f,0.f,0.f,0.f}, v1 = {0.f,0.f,0.f,0.f};
        if (n < N) {
            v0 = *(const float4*)&in[(size_t)(k0 + 2 * kp)     * N + n];
            v1 = *(const float4*)&in[(size_t)(k0 + 2 * kp + 1) * N + n];
        }
        Lds[nq*4+0][kp] = (unsigned)f2bf(v0.x) | ((unsigned)f2bf(v1.x) << 16);
        Lds[nq*4+1][kp] = (unsigned)f2bf(v0.y) | ((unsigned)f2bf(v1.y) << 16);
        Lds[nq*4+2][kp] = (unsigned)f2bf(v0.z) | ((unsigned)f2bf(v1.z) << 16);
        Lds[nq*4+3][kp] = (unsigned)f2bf(v0.w) | ((unsigned)f2bf(v1.w) << 16);
    }
    __syncthreads();

    #pragma unroll
    for (int i = 0; i < 2; ++i) {
        const int c = tid + 256 * i;
        const int n = c >> 3, oct = c & 7;
        uint2 lo = *(uint2*)&Lds[n][oct * 4];
        uint2 hi = *(uint2*)&Lds[n][oct * 4 + 2];
        uint4 v = make_uint4(lo.x, lo.y, hi.x, hi.y);
        *(uint4*)&out[(size_t)(n0 + n) * ldK + k0 + oct * 8] = v;
    }
}

// ---------------------------------------------------------------------------
// Cooperative mega v2: 512 blocks x 256 thr (2 blocks/CU required; LDS 48KB
// allows 3, VGPR<=256 allows 2 -> comfortable margin).
// P1 gemm1 (512 tiles) -> P2 reduce_h + E=b2 + ctr=0 -> P3 gemm2 (320 tiles,
// atomic E) -> P4 scores (1024 tiles, work-stealing, atomic into scores).
// ---------------------------------------------------------------------------
__global__ __launch_bounds__(256, 2) void mega_kernel(
    const unsigned short* __restrict__ Xb,
    const unsigned short* __restrict__ W1T,
    float* __restrict__ Hpart,
    const float* __restrict__ b1,
    unsigned short* __restrict__ Hb,
    const unsigned short* __restrict__ W2T,
    const float* __restrict__ b2,
    float* __restrict__ E,
    const float* __restrict__ G,
    float* __restrict__ scores,
    unsigned int* __restrict__ counter)
{
    __shared__ __align__(16) unsigned char smem[49152];   // 48 KB union
    __shared__ int sVb;

    cg::grid_group grid = cg::this_grid();
    const int tid = threadIdx.x;
    const int blk = blockIdx.x;
    const int lane = tid & 63;
    const int wave = tid >> 6;
    const int q = lane >> 4, l15 = lane & 15;

    // ============ P1: gemm1, 512 tiles (64m x 128n, BK=64), 1 per block =====
    {
        unsigned short (*As)[4096] = (unsigned short(*)[4096])smem;          // 16 KB
        unsigned short (*Bs)[8192] = (unsigned short(*)[8192])(smem + 16384);// 32 KB

        const int bx = blk & 15, by = (blk >> 4) & 7, bz = blk >> 7;
        const int m0 = by * 64, n0 = bx * 128;
        const int kbase = bz * (VFD / G1_SPLIT);

        const unsigned short* ga = Xb  + (size_t)(m0 + (tid & 63)) * VFD + kbase + (tid >> 6) * 8;
        const unsigned short* gb = W1T + (size_t)(n0 + (tid & 127)) * VFD + kbase + (tid >> 7) * 8;

        const int wm = (wave & 1) * 32;
        const int wn = (wave >> 1) * 64;

        f32x4 acc[2][4];
        #pragma unroll
        for (int r = 0; r < 2; ++r)
            #pragma unroll
            for (int c = 0; c < 4; ++c) acc[r][c] = (f32x4){0.f,0.f,0.f,0.f};

        #pragma unroll
        for (int i = 0; i < 2; ++i)
            __builtin_amdgcn_global_load_lds((gas_t)(const void*)(ga + i * 32),
                                             (las_t)(void*)&As[0][(tid + 256 * i) * 8], 16, 0, 0);
        #pragma unroll
        for (int i = 0; i < 4; ++i)
            __builtin_amdgcn_global_load_lds((gas_t)(const void*)(gb + i * 16),
                                             (las_t)(void*)&Bs[0][(tid + 256 * i) * 8], 16, 0, 0);

        const int iters = (VFD / G1_SPLIT) / 64;          // 16
        for (int t = 0; t < iters; ++t) {
            const int cur = t & 1, nxt = cur ^ 1;
            __syncthreads();

            if (t + 1 < iters) {
                const int ko = (t + 1) * 64;
                #pragma unroll
                for (int i = 0; i < 2; ++i)
                    __builtin_amdgcn_global_load_lds((gas_t)(const void*)(ga + ko + i * 32),
                                                     (las_t)(void*)&As[nxt][(tid + 256 * i) * 8], 16, 0, 0);
                #pragma unroll
                for (int i = 0; i < 4; ++i)
                    __builtin_amdgcn_global_load_lds((gas_t)(const void*)(gb + ko + i * 16),
                                                     (las_t)(void*)&Bs[nxt][(tid + 256 * i) * 8], 16, 0, 0);
            }

            #pragma unroll
            for (int kk = 0; kk < 2; ++kk) {
                const int oct = kk * 4 + q;
                short8x a0 = *(short8x*)&As[cur][(oct * 64 + wm +      l15) * 8];
                short8x a1 = *(short8x*)&As[cur][(oct * 64 + wm + 16 + l15) * 8];
                #pragma unroll
                for (int c = 0; c < 4; ++c) {
                    short8x b = *(short8x*)&Bs[cur][(oct * 128 + wn + c * 16 + l15) * 8];
                    acc[0][c] = __builtin_amdgcn_mfma_f32_16x16x32_bf16(a0, b, acc[0][c], 0, 0, 0);
                    acc[1][c] = __builtin_amdgcn_mfma_f32_16x16x32_bf16(a1, b, acc[1][c], 0, 0, 0);
                }
            }
        }

        float* Cz = Hpart + (size_t)bz * B_SZ * HIDD;
        #pragma unroll
        for (int r = 0; r < 2; ++r)
            #pragma unroll
            for (int g = 0; g < 4; ++g) {
                const int rr = m0 + wm + r * 16 + q * 4 + g;
                #pragma unroll
                for (int c = 0; c < 4; ++c)
                    Cz[(size_t)rr * HIDD + n0 + wn + c * 16 + l15] = acc[r][c][g];
            }
    }

    __threadfence();
    grid.sync();

    // ====== P2: reduce_h (1024 slots) + E=b2 (150) + counter=0 (1) ==========
    for (int v = blk; v < 1175; v += 512) {
        if (v < 1024) {
            const int i = (v * 256 + tid) * 4;
            const int col = i & (HIDD - 1);
            float4 s = *(const float4*)&b1[col];
            #pragma unroll
            for (int z = 0; z < G1_SPLIT; ++z) {
                float4 p = *(const float4*)&Hpart[(size_t)z * B_SZ * HIDD + i];
                s.x += p.x; s.y += p.y; s.z += p.z; s.w += p.w;
            }
            ushort4x o;
            o[0] = f2bf(fmaxf(s.x, 0.f));
            o[1] = f2bf(fmaxf(s.y, 0.f));
            o[2] = f2bf(fmaxf(s.z, 0.f));
            o[3] = f2bf(fmaxf(s.w, 0.f));
            *(ushort4x*)&Hb[i] = o;
        } else if (v < 1174) {
            const int j = ((v - 1024) * 256 + tid) * 4;   // 300 % 4 == 0: rows intact
            const int n = j % 300;
            *(float4*)&E[j] = *(const float4*)&b2[n];
        } else if (tid == 0) {
            *counter = 0u;
        }
    }

    __threadfence();
    grid.sync();

    // ============ P3: gemm2, 320 tiles (64m x 64n, BK=64), atomic E =========
    if (blk < 320) {
        unsigned short (*As2)[4096] = (unsigned short(*)[4096])smem;           // 16 KB
        unsigned short (*Bs2)[4096] = (unsigned short(*)[4096])(smem + 16384); // 16 KB

        const int bx = blk % 5, by = (blk / 5) & 7, bz = blk / 40;
        const int m0 = by * 64, n0 = bx * 64;
        const int kbase = bz * (HIDD / G2_SPLIT);

        const unsigned short* ga = Hb  + (size_t)(m0 + (tid & 63)) * HIDD + kbase + (tid >> 6) * 8;
        const unsigned short* gb = W2T + (size_t)(n0 + (tid & 63)) * HIDD + kbase + (tid >> 6) * 8;

        const int wm = (wave & 1) * 32;
        const int wn = (wave >> 1) * 32;

        f32x4 acc00 = {0.f,0.f,0.f,0.f}, acc01 = {0.f,0.f,0.f,0.f};
        f32x4 acc10 = {0.f,0.f,0.f,0.f}, acc11 = {0.f,0.f,0.f,0.f};

        #pragma unroll
        for (int i = 0; i < 2; ++i) {
            __builtin_amdgcn_global_load_lds((gas_t)(const void*)(ga + i * 32),
                                             (las_t)(void*)&As2[0][(tid + 256 * i) * 8], 16, 0, 0);
            __builtin_amdgcn_global_load_lds((gas_t)(const void*)(gb + i * 32),
                                             (las_t)(void*)&Bs2[0][(tid + 256 * i) * 8], 16, 0, 0);
        }

        const int iters = (HIDD / G2_SPLIT) / 64;         // 4
        for (int t = 0; t < iters; ++t) {
            const int cur = t & 1, nxt = cur ^ 1;
            __syncthreads();

            if (t + 1 < iters) {
                const int ko = (t + 1) * 64;
                #pragma unroll
                for (int i = 0; i < 2; ++i) {
                    __builtin_amdgcn_global_load_lds((gas_t)(const void*)(ga + ko + i * 32),
                                                     (las_t)(void*)&As2[nxt][(tid + 256 * i) * 8], 16, 0, 0);
                    __builtin_amdgcn_global_load_lds((gas_t)(const void*)(gb + ko + i * 32),
                                                     (las_t)(void*)&Bs2[nxt][(tid + 256 * i) * 8], 16, 0, 0);
                }
            }

            #pragma unroll
            for (int kk = 0; kk < 2; ++kk) {
                const int oct = kk * 4 + q;
                short8x a0 = *(short8x*)&As2[cur][(oct * 64 + wm +      l15) * 8];
                short8x a1 = *(short8x*)&As2[cur][(oct * 64 + wm + 16 + l15) * 8];
                short8x b0 = *(short8x*)&Bs2[cur][(oct * 64 + wn +      l15) * 8];
                short8x b1 = *(short8x*)&Bs2[cur][(oct * 64 + wn + 16 + l15) * 8];
                acc00 = __builtin_amdgcn_mfma_f32_16x16x32_bf16(a0, b0, acc00, 0, 0, 0);
                acc01 = __builtin_amdgcn_mfma_f32_16x16x32_bf16(a0, b1, acc01, 0, 0, 0);
                acc10 = __builtin_amdgcn_mfma_f32_16x16x32_bf16(a1, b0, acc10, 0, 0, 0);
                acc11 = __builtin_amdgcn_mfma_f32_16x16x32_bf16(a1, b1, acc11, 0, 0, 0);
            }
        }

        const int cc = n0 + wn + l15;
        #pragma unroll
        for (int r = 0; r < 4; ++r) {
            const int rr = m0 + wm + q * 4 + r;
            if (cc < EMBD)      atomicAdd(&E[(size_t)rr * EMBD + cc],        acc00[r]);
            if (cc + 16 < EMBD) atomicAdd(&E[(size_t)rr * EMBD + cc + 16],   acc01[r]);
            if (cc < EMBD)      atomicAdd(&E[(size_t)(rr + 16) * EMBD + cc], acc10[r]);
            if (cc + 16 < EMBD) atomicAdd(&E[(size_t)(rr + 16) * EMBD + cc + 16], acc11[r]);
        }
    }

    __threadfence();
    grid.sync();

    // ============ P4: scores, 1024 tiles (64b x 64n x 80d), work-stealing ===
    {
        float (*Gs)[44] = (float(*)[44])smem;             // 11.3 KB
        const int tx = tid & 15, ty4 = (tid >> 4) * 4;

        for (;;) {
            if (tid == 0) sVb = (int)atomicAdd(counter, 1u);
            __syncthreads();
            const int v = sVb;
            if (v >= 1024) break;

            const int n0 = (v & 31) * 64;
            const int b0 = ((v >> 5) & 7) * 64;
            const int dbase = (v >> 8) * 80;

            float acc[4][4] = {};

            for (int dc = 0; dc < 80; dc += 40) {
                const int d0 = dbase + dc;
                __syncthreads();                          // prev users of Gs done
                #pragma unroll
                for (int i = 0; i < 3; ++i) {
                    const int s = tid + 256 * i;
                    if (s < 640) {
                        const int row = s / 10, qd = (s - row * 10) * 4;
                        const int d = d0 + qd;
                        const int n = n0 + row;
                        float4 vv = {0.f, 0.f, 0.f, 0.f};
                        if (n < NLAB && d < EMBD) vv = *(const float4*)&G[(size_t)n * EMBD + d];
                        *(float4*)&Gs[row][qd] = vv;
                    }
                }
                __syncthreads();

                #pragma unroll 2
                for (int d = 0; d < 40; d += 4) {
                    const int dd = d0 + d;
                    float4 e[4];
                    if (dd < EMBD) {
                        #pragma unroll
                        for (int r = 0; r < 4; ++r)
                            e[r] = *(const float4*)&E[(size_t)(b0 + ty4 + r) * EMBD + dd];
                    } else {
                        #pragma unroll
                        for (int r = 0; r < 4; ++r) e[r] = make_float4(0.f, 0.f, 0.f, 0.f);
                    }
                    #pragma unroll
                    for (int c = 0; c < 4; ++c) {
                        float4 g = *(float4*)&Gs[tx + 16 * c][d];
                        #pragma unroll
                        for (int r = 0; r < 4; ++r) {
                            float t;
                            t = fmaxf(e[r].x - g.x, 0.f); acc[r][c] += t * t;
                            t = fmaxf(e[r].y - g.y, 0.f); acc[r][c] += t * t;
                            t = fmaxf(e[r].z - g.z, 0.f); acc[r][c] += t * t;
                            t = fmaxf(e[r].w - g.w, 0.f); acc[r][c] += t * t;
                        }
                    }
                }
            }

            #pragma unroll
            for (int r = 0; r < 4; ++r) {
                const int b = b0 + ty4 + r;
                #pragma unroll
                for (int c = 0; c < 4; ++c) {
                    const int n = n0 + tx + 16 * c;
                    if (n < NLAB) atomicAdd(&scores[(size_t)b * NLAB + n], -acc[r][c]);
                }
            }
        }
    }
}

// =========================== FALLBACK PATH (r8) =============================
__global__ __launch_bounds__(256) void gemm1_kernel(
    const unsigned short* __restrict__ A,
    const unsigned short* __restrict__ Bt,
    float* __restrict__ Cpart)
{
    __shared__ unsigned short As[2][4096];
    __shared__ unsigned short Bs[2][8192];

    const int tid = threadIdx.x;
    const int m0 = blockIdx.y * 64, n0 = blockIdx.x * 128;
    const int kbase = blockIdx.z * (VFD / G1_SPLIT);

    const unsigned short* ga = A + (size_t)(m0 + (tid & 63)) * VFD + kbase + (tid >> 6) * 8;
    const unsigned short* gb = Bt + (size_t)(n0 + (tid & 127)) * VFD + kbase + (tid >> 7) * 8;

    const int lane = tid & 63;
    const int wave = tid >> 6;
    const int wm = (wave & 1) * 32;
    const int wn = (wave >> 1) * 64;
    const int q = lane >> 4, l15 = lane & 15;

    f32x4 acc[2][4];
    #pragma unroll
    for (int r = 0; r < 2; ++r)
        #pragma unroll
        for (int c = 0; c < 4; ++c) acc[r][c] = (f32x4){0.f,0.f,0.f,0.f};

    #pragma unroll
    for (int i = 0; i < 2; ++i)
        __builtin_amdgcn_global_load_lds((gas_t)(const void*)(ga + i * 32),
                                         (las_t)(void*)&As[0][(tid + 256 * i) * 8], 16, 0, 0);
    #pragma unroll
    for (int i = 0; i < 4; ++i)
        __builtin_amdgcn_global_load_lds((gas_t)(const void*)(gb + i * 16),
                                         (las_t)(void*)&Bs[0][(tid + 256 * i) * 8], 16, 0, 0);

    const int iters = (VFD / G1_SPLIT) / 64;
    for (int t = 0; t < iters; ++t) {
        const int cur = t & 1, nxt = cur ^ 1;
        __syncthreads();

        if (t + 1 < iters) {
            const int ko = (t + 1) * 64;
            #pragma unroll
            for (int i = 0; i < 2; ++i)
                __builtin_amdgcn_global_load_lds((gas_t)(const void*)(ga + ko + i * 32),
                                                 (las_t)(void*)&As[nxt][(tid + 256 * i) * 8], 16, 0, 0);
            #pragma unroll
            for (int i = 0; i < 4; ++i)
                __builtin_amdgcn_global_load_lds((gas_t)(const void*)(gb + ko + i * 16),
                                                 (las_t)(void*)&Bs[nxt][(tid + 256 * i) * 8], 16, 0, 0);
        }

        #pragma unroll
        for (int kk = 0; kk < 2; ++kk) {
            const int oct = kk * 4 + q;
            short8x a0 = *(short8x*)&As[cur][(oct * 64 + wm +      l15) * 8];
            short8x a1 = *(short8x*)&As[cur][(oct * 64 + wm + 16 + l15) * 8];
            #pragma unroll
            for (int c = 0; c < 4; ++c) {
                short8x b = *(short8x*)&Bs[cur][(oct * 128 + wn + c * 16 + l15) * 8];
                acc[0][c] = __builtin_amdgcn_mfma_f32_16x16x32_bf16(a0, b, acc[0][c], 0, 0, 0);
                acc[1][c] = __builtin_amdgcn_mfma_f32_16x16x32_bf16(a1, b, acc[1][c], 0, 0, 0);
            }
        }
    }

    float* Cz = Cpart + (size_t)blockIdx.z * B_SZ * HIDD;
    #pragma unroll
    for (int r = 0; r < 2; ++r)
        #pragma unroll
        for (int g = 0; g < 4; ++g) {
            const int rr = m0 + wm + r * 16 + q * 4 + g;
            #pragma unroll
            for (int c = 0; c < 4; ++c)
                Cz[(size_t)rr * HIDD + n0 + wn + c * 16 + l15] = acc[r][c][g];
        }
}

template<int LDA, int LDB, int LDC, int KCHUNK>
__global__ __launch_bounds__(256) void gemm_bf16_kernel(
    const unsigned short* __restrict__ A,
    const unsigned short* __restrict__ Bt,
    float* __restrict__ Cpart, int M)
{
    __shared__ unsigned short As[2][4096];
    __shared__ unsigned short Bs[2][4096];

    const int tid = threadIdx.x;
    const int m0 = blockIdx.y * 64, n0 = blockIdx.x * 64;
    const int kbase = blockIdx.z * KCHUNK;

    const unsigned short* ga = A  + (size_t)(m0 + (tid & 63)) * LDA + kbase + (tid >> 6) * 8;
    const unsigned short* gb = Bt + (size_t)(n0 + (tid & 63)) * LDB + kbase + (tid >> 6) * 8;

    const int lane = tid & 63;
    const int wave = tid >> 6;
    const int wm = (wave & 1) * 32;
    const int wn = (wave >> 1) * 32;
    const int q = lane >> 4, l15 = lane & 15;

    f32x4 acc00 = {0.f,0.f,0.f,0.f}, acc01 = {0.f,0.f,0.f,0.f};
    f32x4 acc10 = {0.f,0.f,0.f,0.f}, acc11 = {0.f,0.f,0.f,0.f};

    #pragma unroll
    for (int i = 0; i < 2; ++i) {
        __builtin_amdgcn_global_load_lds((gas_t)(const void*)(ga + i * 32),
                                         (las_t)(void*)&As[0][(tid + 256 * i) * 8], 16, 0, 0);
        __builtin_amdgcn_global_load_lds((gas_t)(const void*)(gb + i * 32),
                                         (las_t)(void*)&Bs[0][(tid + 256 * i) * 8], 16, 0, 0);
    }

    const int iters = KCHUNK / 64;
    for (int t = 0; t < iters; ++t) {
        const int cur = t & 1, nxt = cur ^ 1;
        __syncthreads();

        if (t + 1 < iters) {
            const int ko = (t + 1) * 64;
            #pragma unroll
            for (int i = 0; i < 2; ++i) {
                __builtin_amdgcn_global_load_lds((gas_t)(const void*)(ga + ko + i * 32),
                                                 (las_t)(void*)&As[nxt][(tid + 256 * i) * 8], 16, 0, 0);
                __builtin_amdgcn_global_load_lds((gas_t)(const void*)(gb + ko + i * 32),
                                                 (las_t)(void*)&Bs[nxt][(tid + 256 * i) * 8], 16, 0, 0);
            }
        }

        #pragma unroll
        for (int kk = 0; kk < 2; ++kk) {
            const int oct = kk * 4 + q;
            short8x a0 = *(short8x*)&As[cur][(oct * 64 + wm +      l15) * 8];
            short8x a1 = *(short8x*)&As[cur][(oct * 64 + wm + 16 + l15) * 8];
            short8x b0 = *(short8x*)&Bs[cur][(oct * 64 + wn +      l15) * 8];
            short8x b1 = *(short8x*)&Bs[cur][(oct * 64 + wn + 16 + l15) * 8];
            acc00 = __builtin_amdgcn_mfma_f32_16x16x32_bf16(a0, b0, acc00, 0, 0, 0);
            acc01 = __builtin_amdgcn_mfma_f32_16x16x32_bf16(a0, b1, acc01, 0, 0, 0);
            acc10 = __builtin_amdgcn_mfma_f32_16x16x32_bf16(a1, b0, acc10, 0, 0, 0);
            acc11 = __builtin_amdgcn_mfma_f32_16x16x32_bf16(a1, b1, acc11, 0, 0, 0);
        }
    }

    float* Cz = Cpart + (size_t)blockIdx.z * M * LDC;
    #pragma unroll
    for (int r = 0; r < 4; ++r) {
        const int rr = m0 + wm + q * 4 + r;
        const int cc = n0 + wn + l15;
        Cz[(size_t)rr * LDC + cc]             = acc00[r];
        Cz[(size_t)rr * LDC + cc + 16]        = acc01[r];
        Cz[(size_t)(rr + 16) * LDC + cc]      = acc10[r];
        Cz[(size_t)(rr + 16) * LDC + cc + 16] = acc11[r];
    }
}

__global__ __launch_bounds__(256) void reduce_h_kernel(
    const float* __restrict__ Hpart, const float* __restrict__ b1,
    unsigned short* __restrict__ Hb)
{
    const int i = (blockIdx.x * 256 + threadIdx.x) * 4;
    const int col = i & (HIDD - 1);
    float4 s = *(const float4*)&b1[col];
    #pragma unroll
    for (int z = 0; z < G1_SPLIT; ++z) {
        float4 p = *(const float4*)&Hpart[(size_t)z * B_SZ * HIDD + i];
        s.x += p.x; s.y += p.y; s.z += p.z; s.w += p.w;
    }
    ushort4x o;
    o[0] = f2bf(fmaxf(s.x, 0.f));
    o[1] = f2bf(fmaxf(s.y, 0.f));
    o[2] = f2bf(fmaxf(s.z, 0.f));
    o[3] = f2bf(fmaxf(s.w, 0.f));
    *(ushort4x*)&Hb[i] = o;
}

__global__ __launch_bounds__(256) void reduce_e_kernel(
    const float* __restrict__ Epart, const float* __restrict__ b2,
    float* __restrict__ E)
{
    const int gid = blockIdx.x * 256 + threadIdx.x;
    if (gid >= B_SZ * EMBD) return;
    const int m = gid / EMBD, n = gid - m * EMBD;
    float v = b2[n];
    #pragma unroll
    for (int z = 0; z < G2_SPLIT; ++z)
        v += Epart[(size_t)z * B_SZ * NPAD + m * NPAD + n];
    E[gid] = v;
}

__global__ __launch_bounds__(128) void scores_part_kernel(
    const float* __restrict__ E, const float* __restrict__ G,
    float* __restrict__ scores)
{
    __shared__ float Gs[64][44];

    const int tid = threadIdx.x;
    const int tx = tid & 15, ty = tid >> 4;
    const int n0 = blockIdx.x * 64, b0 = blockIdx.y * 32;
    const int dbase = blockIdx.z * (NPAD / SD_SPLIT);

    float acc[4][4] = {};

    for (int dc = 0; dc < NPAD / SD_SPLIT; dc += 40) {
        const int d0 = dbase + dc;
        __syncthreads();
        #pragma unroll
        for (int i = 0; i < 5; ++i) {
            const int s = tid + 128 * i;
            const int row = s / 10, qd = (s - row * 10) * 4;
            const int d = d0 + qd;
            const int n = n0 + row;
            float4 v = {0.f, 0.f, 0.f, 0.f};
            if (n < NLAB && d < EMBD) v = *(const float4*)&G[(size_t)n * EMBD + d];
            *(float4*)&Gs[row][qd] = v;
        }
        __syncthreads();

        #pragma unroll 2
        for (int d = 0; d < 40; d += 4) {
            const int dd = d0 + d;
            float4 e[4];
            if (dd < EMBD) {
                #pragma unroll
                for (int r = 0; r < 4; ++r)
                    e[r] = *(const float4*)&E[(size_t)(b0 + ty * 4 + r) * EMBD + dd];
            } else {
                #pragma unroll
                for (int r = 0; r < 4; ++r) e[r] = make_float4(0.f, 0.f, 0.f, 0.f);
            }
            #pragma unroll
            for (int c = 0; c < 4; ++c) {
                float4 g = *(float4*)&Gs[tx + 16 * c][d];
                #pragma unroll
                for (int r = 0; r < 4; ++r) {
                    float t;
                    t = fmaxf(e[r].x - g.x, 0.f); acc[r][c] += t * t;
                    t = fmaxf(e[r].y - g.y, 0.f); acc[r][c] += t * t;
                    t = fmaxf(e[r].z - g.z, 0.f); acc[r][c] += t * t;
                    t = fmaxf(e[r].w - g.w, 0.f); acc[r][c] += t * t;
                }
            }
        }
    }

    #pragma unroll
    for (int r = 0; r < 4; ++r) {
        const int b = b0 + ty * 4 + r;
        #pragma unroll
        for (int c = 0; c < 4; ++c) {
            const int n = n0 + tx + 16 * c;
            if (n < NLAB) atomicAdd(&scores[(size_t)b * NLAB + n], -acc[r][c]);
        }
    }
}

// ---------------------------------------------------------------------------
extern "C" void kernel_launch(void* const* d_in, const int* in_sizes, int n_in,
                              void* d_out, int out_size, void* d_ws, size_t ws_size,
                              hipStream_t stream)
{
    const float* vfs = (const float*)d_in[0];   // [512,4096]
    const float* W1  = (const float*)d_in[1];   // [4096,2048]
    const float* b1  = (const float*)d_in[2];   // [2048]
    const float* W2  = (const float*)d_in[3];   // [2048,300]
    const float* b2  = (const float*)d_in[4];   // [300]
    const float* G   = (const float*)d_in[5];   // [2000,300]

    float* out    = (float*)d_out;
    float* scores = out;                        // [512*2000]
    float* E      = out + (size_t)B_SZ * NLAB;  // [512*300]

    char* ws = (char*)d_ws;
    unsigned short* Xb  = (unsigned short*)(ws);             //  4 MB   [512][4096]
    unsigned short* W1T = (unsigned short*)(ws + 4194304);   // 16 MB   [2048][4096]
    unsigned short* W2T = (unsigned short*)(ws + 20971520);  // 1.25 MB [320][2048]
    unsigned short* Hb  = (unsigned short*)(ws + 22282240);  //  2 MB   [512][2048]
    float*          Hpart = (float*)(ws + 24379392);         // 16 MB   [4][512][2048]
    float*          Epart = (float*)(ws + 41156608);         // 5.25 MB [8][512][320]
    unsigned int*   counter = (unsigned int*)(ws + 47185920);

    prep_kernel<<<4256, 256, 0, stream>>>(vfs, Xb, W1, W1T, W2, W2T, scores);

    const unsigned short* Xb_c  = Xb;
    const unsigned short* W1T_c = W1T;
    const unsigned short* W2T_c = W2T;
    void* kargs[] = {
        (void*)&Xb_c, (void*)&W1T_c, (void*)&Hpart, (void*)&b1, (void*)&Hb,
        (void*)&W2T_c, (void*)&b2, (void*)&E, (void*)&G, (void*)&scores,
        (void*)&counter
    };
    hipError_t cerr = hipLaunchCooperativeKernel((void*)mega_kernel, dim3(512),
                                                 dim3(256), kargs, 0, stream);
    if (cerr != hipSuccess) {
        // deterministic fallback: proven r8 multi-kernel chain
        gemm1_kernel<<<dim3(16, 8, G1_SPLIT), 256, 0, stream>>>(Xb, W1T, Hpart);
        reduce_h_kernel<<<1024, 256, 0, stream>>>(Hpart, b1, Hb);
        gemm_bf16_kernel<HIDD, HIDD, NPAD, HIDD / G2_SPLIT>
            <<<dim3(5, 8, G2_SPLIT), 256, 0, stream>>>(Hb, W2T, Epart, B_SZ);
        reduce_e_kernel<<<600, 256, 0, stream>>>(Epart, b2, E);
        scores_part_kernel<<<dim3(32, 16, SD_SPLIT), 128, 0, stream>>>(E, G, scores);
    }
}

// Round 11
// 195.006 us; speedup vs baseline: 2.6375x; 2.6375x over previous
//
#include <hip/hip_runtime.h>

#define B_SZ   512
#define VFD    4096
#define HIDD   2048
#define EMBD   300
#define NLAB   2000
#define NPAD   320

#define G2_SPLIT 8          // gemm2 k-chunks: K=2048 -> 256 each, 320 blocks
#define SD_SPLIT 4          // scores d-quarters: 320 -> 80 dims each

typedef __attribute__((ext_vector_type(8))) short short8x;
typedef __attribute__((ext_vector_type(4))) float f32x4;
typedef __attribute__((ext_vector_type(8))) unsigned short ushort8;

typedef const __attribute__((address_space(1))) unsigned int* gas_t;
typedef __attribute__((address_space(3))) unsigned int* las_t;

__device__ inline unsigned short f2bf(float x) {
    unsigned u = __float_as_uint(x);
    u += 0x7FFF + ((u >> 16) & 1);          // round-to-nearest-even
    return (unsigned short)(u >> 16);
}

// ---------------------------------------------------------------------------
// Prep (4382 blocks):
//   [0,1024):     Xb = bf16(relu(vfs))
//   [1024,3072):  W1T[n][k] = bf16(W1[k][n])  (pair-packed transpose)
//   [3072,3232):  W2T[n][k] = bf16(W2[k][n]), n>=300 zero-padded
//   [3232,4232):  scores <- 0   (atomic target for scores_part)
//   [4232,4382):  E[m][n] <- b2[n]  (atomic target for gemm2)
// ---------------------------------------------------------------------------
__global__ __launch_bounds__(256) void prep_kernel(
    const float* __restrict__ vfs, unsigned short* __restrict__ Xb,
    const float* __restrict__ W1, unsigned short* __restrict__ W1T,
    const float* __restrict__ W2, unsigned short* __restrict__ W2T,
    float* __restrict__ scores, const float* __restrict__ b2,
    float* __restrict__ E)
{
    __shared__ unsigned int Lds[64][34];
    const int tid = threadIdx.x;
    const int blk = blockIdx.x;

    if (blk < 1024) {
        const int i = (blk * 256 + tid) * 8;
        float4 a = *(const float4*)&vfs[i];
        float4 b = *(const float4*)&vfs[i + 4];
        ushort8 o;
        o[0] = f2bf(fmaxf(a.x, 0.f)); o[1] = f2bf(fmaxf(a.y, 0.f));
        o[2] = f2bf(fmaxf(a.z, 0.f)); o[3] = f2bf(fmaxf(a.w, 0.f));
        o[4] = f2bf(fmaxf(b.x, 0.f)); o[5] = f2bf(fmaxf(b.y, 0.f));
        o[6] = f2bf(fmaxf(b.z, 0.f)); o[7] = f2bf(fmaxf(b.w, 0.f));
        *(ushort8*)&Xb[i] = o;
        return;
    }
    if (blk >= 4232) {                      // E = b2 (row-major [512][300])
        const int j = ((blk - 4232) * 256 + tid) * 4;   // j%4==0, 300%4==0
        if (j < B_SZ * EMBD) {
            const int n = j % EMBD;
            *(float4*)&E[j] = *(const float4*)&b2[n];
        }
        return;
    }
    if (blk >= 3232) {                      // scores = 0
        const int i = ((blk - 3232) * 256 + tid) * 4;
        if (i < B_SZ * NLAB) {
            float4 z = {0.f, 0.f, 0.f, 0.f};
            *(float4*)&scores[i] = z;
        }
        return;
    }

    const float* in; unsigned short* out; int N, ldK, bx, by;
    if (blk < 3072) {                       // W1: K=4096, N=2048, tiles (32,64)
        const int b = blk - 1024;
        in = W1; out = W1T; N = HIDD; ldK = VFD; bx = b & 31; by = b >> 5;
    } else {                                // W2: K=2048, N=300->320, tiles (5,32)
        const int b = blk - 3072;
        in = W2; out = W2T; N = EMBD; ldK = HIDD; bx = b % 5; by = b / 5;
    }
    const int n0 = bx * 64, k0 = by * 64;

    #pragma unroll
    for (int i = 0; i < 2; ++i) {
        const int s = tid + 256 * i;
        const int kp = s >> 4, nq = s & 15;
        const int n = n0 + nq * 4;
        float4 v0 = {0.f,0.f,0.f,0.f}, v1 = {0.f,0.f,0.f,0.f};
        if (n < N) {
            v0 = *(const float4*)&in[(size_t)(k0 + 2 * kp)     * N + n];
            v1 = *(const float4*)&in[(size_t)(k0 + 2 * kp + 1) * N + n];
        }
        Lds[nq*4+0][kp] = (unsigned)f2bf(v0.x) | ((unsigned)f2bf(v1.x) << 16);
        Lds[nq*4+1][kp] = (unsigned)f2bf(v0.y) | ((unsigned)f2bf(v1.y) << 16);
        Lds[nq*4+2][kp] = (unsigned)f2bf(v0.z) | ((unsigned)f2bf(v1.z) << 16);
        Lds[nq*4+3][kp] = (unsigned)f2bf(v0.w) | ((unsigned)f2bf(v1.w) << 16);
    }
    __syncthreads();

    #pragma unroll
    for (int i = 0; i < 2; ++i) {
        const int c = tid + 256 * i;
        const int n = c >> 3, oct = c & 7;
        uint2 lo = *(uint2*)&Lds[n][oct * 4];
        uint2 hi = *(uint2*)&Lds[n][oct * 4 + 2];
        uint4 v = make_uint4(lo.x, lo.y, hi.x, hi.y);
        *(uint4*)&out[(size_t)(n0 + n) * ldK + k0 + oct * 8] = v;
    }
}

// ---------------------------------------------------------------------------
// GEMM1 (un-split, fused epilogue): Hb[512][2048] = bf16(relu(Xb @ W1T^T + b1)).
// Tile 64m x 64n, full K=4096, BK=64, dbuf global_load_lds, grid (32,8)=256.
// 4 waves of 32x32 (2x2 mfma 16x16x32). No Hpart, no reduce_h.
// ---------------------------------------------------------------------------
__global__ __launch_bounds__(256) void gemm1_kernel(
    const unsigned short* __restrict__ A,
    const unsigned short* __restrict__ Bt,
    const float* __restrict__ b1,
    unsigned short* __restrict__ Hb)
{
    __shared__ unsigned short As[2][4096];   // 8 oct x 64 rows (8 KB each buf)
    __shared__ unsigned short Bs[2][4096];

    const int tid = threadIdx.x;
    const int m0 = blockIdx.y * 64, n0 = blockIdx.x * 64;

    const unsigned short* ga = A  + (size_t)(m0 + (tid & 63)) * VFD + (tid >> 6) * 8;
    const unsigned short* gb = Bt + (size_t)(n0 + (tid & 63)) * VFD + (tid >> 6) * 8;

    const int lane = tid & 63;
    const int wave = tid >> 6;
    const int wm = (wave & 1) * 32;
    const int wn = (wave >> 1) * 32;
    const int q = lane >> 4, l15 = lane & 15;

    f32x4 acc00 = {0.f,0.f,0.f,0.f}, acc01 = {0.f,0.f,0.f,0.f};
    f32x4 acc10 = {0.f,0.f,0.f,0.f}, acc11 = {0.f,0.f,0.f,0.f};

    #pragma unroll
    for (int i = 0; i < 2; ++i) {
        __builtin_amdgcn_global_load_lds((gas_t)(const void*)(ga + i * 32),
                                         (las_t)(void*)&As[0][(tid + 256 * i) * 8], 16, 0, 0);
        __builtin_amdgcn_global_load_lds((gas_t)(const void*)(gb + i * 32),
                                         (las_t)(void*)&Bs[0][(tid + 256 * i) * 8], 16, 0, 0);
    }

    const int iters = VFD / 64;              // 64
    for (int t = 0; t < iters; ++t) {
        const int cur = t & 1, nxt = cur ^ 1;
        __syncthreads();            // vmcnt drain: tile t present; buf[nxt] free

        if (t + 1 < iters) {
            const int ko = (t + 1) * 64;
            #pragma unroll
            for (int i = 0; i < 2; ++i) {
                __builtin_amdgcn_global_load_lds((gas_t)(const void*)(ga + ko + i * 32),
                                                 (las_t)(void*)&As[nxt][(tid + 256 * i) * 8], 16, 0, 0);
                __builtin_amdgcn_global_load_lds((gas_t)(const void*)(gb + ko + i * 32),
                                                 (las_t)(void*)&Bs[nxt][(tid + 256 * i) * 8], 16, 0, 0);
            }
        }

        #pragma unroll
        for (int kk = 0; kk < 2; ++kk) {
            const int oct = kk * 4 + q;
            short8x a0 = *(short8x*)&As[cur][(oct * 64 + wm +      l15) * 8];
            short8x a1 = *(short8x*)&As[cur][(oct * 64 + wm + 16 + l15) * 8];
            short8x b0 = *(short8x*)&Bs[cur][(oct * 64 + wn +      l15) * 8];
            short8x b1 = *(short8x*)&Bs[cur][(oct * 64 + wn + 16 + l15) * 8];
            acc00 = __builtin_amdgcn_mfma_f32_16x16x32_bf16(a0, b0, acc00, 0, 0, 0);
            acc01 = __builtin_amdgcn_mfma_f32_16x16x32_bf16(a0, b1, acc01, 0, 0, 0);
            acc10 = __builtin_amdgcn_mfma_f32_16x16x32_bf16(a1, b0, acc10, 0, 0, 0);
            acc11 = __builtin_amdgcn_mfma_f32_16x16x32_bf16(a1, b1, acc11, 0, 0, 0);
        }
    }

    // fused epilogue: + b1, relu, bf16-cast, store Hb
    const int cc = n0 + wn + l15;
    const float bL = b1[cc], bH = b1[cc + 16];
    #pragma unroll
    for (int r = 0; r < 4; ++r) {
        const int rr = m0 + wm + q * 4 + r;
        Hb[(size_t)rr * HIDD + cc]             = f2bf(fmaxf(acc00[r] + bL, 0.f));
        Hb[(size_t)rr * HIDD + cc + 16]        = f2bf(fmaxf(acc01[r] + bH, 0.f));
        Hb[(size_t)(rr + 16) * HIDD + cc]      = f2bf(fmaxf(acc10[r] + bL, 0.f));
        Hb[(size_t)(rr + 16) * HIDD + cc + 16] = f2bf(fmaxf(acc11[r] + bH, 0.f));
    }
}

// ---------------------------------------------------------------------------
// GEMM2 (split-K, atomic): E[m][n] += (Hb @ W2T^T chunk z), E pre-init = b2.
// Tile 64m x 64n, BK=64 (4 iters), grid (5, 8, 8) = 320 blocks.
// ---------------------------------------------------------------------------
__global__ __launch_bounds__(256) void gemm2_kernel(
    const unsigned short* __restrict__ A,
    const unsigned short* __restrict__ Bt,
    float* __restrict__ E)
{
    __shared__ unsigned short As[2][4096];
    __shared__ unsigned short Bs[2][4096];

    const int tid = threadIdx.x;
    const int m0 = blockIdx.y * 64, n0 = blockIdx.x * 64;
    const int kbase = blockIdx.z * (HIDD / G2_SPLIT);

    const unsigned short* ga = A  + (size_t)(m0 + (tid & 63)) * HIDD + kbase + (tid >> 6) * 8;
    const unsigned short* gb = Bt + (size_t)(n0 + (tid & 63)) * HIDD + kbase + (tid >> 6) * 8;

    const int lane = tid & 63;
    const int wave = tid >> 6;
    const int wm = (wave & 1) * 32;
    const int wn = (wave >> 1) * 32;
    const int q = lane >> 4, l15 = lane & 15;

    f32x4 acc00 = {0.f,0.f,0.f,0.f}, acc01 = {0.f,0.f,0.f,0.f};
    f32x4 acc10 = {0.f,0.f,0.f,0.f}, acc11 = {0.f,0.f,0.f,0.f};

    #pragma unroll
    for (int i = 0; i < 2; ++i) {
        __builtin_amdgcn_global_load_lds((gas_t)(const void*)(ga + i * 32),
                                         (las_t)(void*)&As[0][(tid + 256 * i) * 8], 16, 0, 0);
        __builtin_amdgcn_global_load_lds((gas_t)(const void*)(gb + i * 32),
                                         (las_t)(void*)&Bs[0][(tid + 256 * i) * 8], 16, 0, 0);
    }

    const int iters = (HIDD / G2_SPLIT) / 64;            // 4
    for (int t = 0; t < iters; ++t) {
        const int cur = t & 1, nxt = cur ^ 1;
        __syncthreads();

        if (t + 1 < iters) {
            const int ko = (t + 1) * 64;
            #pragma unroll
            for (int i = 0; i < 2; ++i) {
                __builtin_amdgcn_global_load_lds((gas_t)(const void*)(ga + ko + i * 32),
                                                 (las_t)(void*)&As[nxt][(tid + 256 * i) * 8], 16, 0, 0);
                __builtin_amdgcn_global_load_lds((gas_t)(const void*)(gb + ko + i * 32),
                                                 (las_t)(void*)&Bs[nxt][(tid + 256 * i) * 8], 16, 0, 0);
            }
        }

        #pragma unroll
        for (int kk = 0; kk < 2; ++kk) {
            const int oct = kk * 4 + q;
            short8x a0 = *(short8x*)&As[cur][(oct * 64 + wm +      l15) * 8];
            short8x a1 = *(short8x*)&As[cur][(oct * 64 + wm + 16 + l15) * 8];
            short8x b0 = *(short8x*)&Bs[cur][(oct * 64 + wn +      l15) * 8];
            short8x b1 = *(short8x*)&Bs[cur][(oct * 64 + wn + 16 + l15) * 8];
            acc00 = __builtin_amdgcn_mfma_f32_16x16x32_bf16(a0, b0, acc00, 0, 0, 0);
            acc01 = __builtin_amdgcn_mfma_f32_16x16x32_bf16(a0, b1, acc01, 0, 0, 0);
            acc10 = __builtin_amdgcn_mfma_f32_16x16x32_bf16(a1, b0, acc10, 0, 0, 0);
            acc11 = __builtin_amdgcn_mfma_f32_16x16x32_bf16(a1, b1, acc11, 0, 0, 0);
        }
    }

    const int cc = n0 + wn + l15;
    #pragma unroll
    for (int r = 0; r < 4; ++r) {
        const int rr = m0 + wm + q * 4 + r;
        if (cc < EMBD)      atomicAdd(&E[(size_t)rr * EMBD + cc],        acc00[r]);
        if (cc + 16 < EMBD) atomicAdd(&E[(size_t)rr * EMBD + cc + 16],   acc01[r]);
        if (cc < EMBD)      atomicAdd(&E[(size_t)(rr + 16) * EMBD + cc], acc10[r]);
        if (cc + 16 < EMBD) atomicAdd(&E[(size_t)(rr + 16) * EMBD + cc + 16], acc11[r]);
    }
}

// ---------------------------------------------------------------------------
// Scores partials: atomicAdd(scores[b][n], -sum_{d in quarter} relu(E-G)^2).
// Tile 32 b x 64 n, 128 threads, thread = 4 rows x 4 labels.
// Grid (32, 16, SD_SPLIT) = 2048 blocks.
// ---------------------------------------------------------------------------
__global__ __launch_bounds__(128) void scores_part_kernel(
    const float* __restrict__ E, const float* __restrict__ G,
    float* __restrict__ scores)
{
    __shared__ float Gs[64][44];

    const int tid = threadIdx.x;
    const int tx = tid & 15, ty = tid >> 4;
    const int n0 = blockIdx.x * 64, b0 = blockIdx.y * 32;
    const int dbase = blockIdx.z * (NPAD / SD_SPLIT);

    float acc[4][4] = {};

    for (int dc = 0; dc < NPAD / SD_SPLIT; dc += 40) {
        const int d0 = dbase + dc;
        __syncthreads();
        #pragma unroll
        for (int i = 0; i < 5; ++i) {
            const int s = tid + 128 * i;
            const int row = s / 10, qd = (s - row * 10) * 4;
            const int d = d0 + qd;
            const int n = n0 + row;
            float4 v = {0.f, 0.f, 0.f, 0.f};
            if (n < NLAB && d < EMBD) v = *(const float4*)&G[(size_t)n * EMBD + d];
            *(float4*)&Gs[row][qd] = v;
        }
        __syncthreads();

        #pragma unroll 2
        for (int d = 0; d < 40; d += 4) {
            const int dd = d0 + d;
            float4 e[4];
            if (dd < EMBD) {
                #pragma unroll
                for (int r = 0; r < 4; ++r)
                    e[r] = *(const float4*)&E[(size_t)(b0 + ty * 4 + r) * EMBD + dd];
            } else {
                #pragma unroll
                for (int r = 0; r < 4; ++r) e[r] = make_float4(0.f, 0.f, 0.f, 0.f);
            }
            #pragma unroll
            for (int c = 0; c < 4; ++c) {
                float4 g = *(float4*)&Gs[tx + 16 * c][d];
                #pragma unroll
                for (int r = 0; r < 4; ++r) {
                    float t;
                    t = fmaxf(e[r].x - g.x, 0.f); acc[r][c] += t * t;
                    t = fmaxf(e[r].y - g.y, 0.f); acc[r][c] += t * t;
                    t = fmaxf(e[r].z - g.z, 0.f); acc[r][c] += t * t;
                    t = fmaxf(e[r].w - g.w, 0.f); acc[r][c] += t * t;
                }
            }
        }
    }

    #pragma unroll
    for (int r = 0; r < 4; ++r) {
        const int b = b0 + ty * 4 + r;
        #pragma unroll
        for (int c = 0; c < 4; ++c) {
            const int n = n0 + tx + 16 * c;
            if (n < NLAB) atomicAdd(&scores[(size_t)b * NLAB + n], -acc[r][c]);
        }
    }
}

// ---------------------------------------------------------------------------
extern "C" void kernel_launch(void* const* d_in, const int* in_sizes, int n_in,
                              void* d_out, int out_size, void* d_ws, size_t ws_size,
                              hipStream_t stream)
{
    const float* vfs = (const float*)d_in[0];   // [512,4096]
    const float* W1  = (const float*)d_in[1];   // [4096,2048]
    const float* b1  = (const float*)d_in[2];   // [2048]
    const float* W2  = (const float*)d_in[3];   // [2048,300]
    const float* b2  = (const float*)d_in[4];   // [300]
    const float* G   = (const float*)d_in[5];   // [2000,300]

    float* out    = (float*)d_out;
    float* scores = out;                        // [512*2000]
    float* E      = out + (size_t)B_SZ * NLAB;  // [512*300]

    // workspace layout (bytes): ~23.3 MB used
    char* ws = (char*)d_ws;
    unsigned short* Xb  = (unsigned short*)(ws);             //  4 MB   [512][4096]
    unsigned short* W1T = (unsigned short*)(ws + 4194304);   // 16 MB   [2048][4096]
    unsigned short* W2T = (unsigned short*)(ws + 20971520);  // 1.25 MB [320][2048]
    unsigned short* Hb  = (unsigned short*)(ws + 22282240);  //  2 MB   [512][2048]

    // prep: Xb (1024) + W1T (2048) + W2T (160) + scores=0 (1000) + E=b2 (150)
    prep_kernel<<<4382, 256, 0, stream>>>(vfs, Xb, W1, W1T, W2, W2T,
                                          scores, b2, E);

    // GEMM1: full-K, fused bias+relu+bf16 epilogue -> Hb. Grid (32,8)=256.
    gemm1_kernel<<<dim3(32, 8), 256, 0, stream>>>(Xb, W1T, b1, Hb);

    // GEMM2: split-K 8, atomic into E (pre-init b2). Grid (5,8,8)=320.
    gemm2_kernel<<<dim3(5, 8, G2_SPLIT), 256, 0, stream>>>(Hb, W2T, E);

    // Scores: 2048 blocks, atomic into scores (pre-init 0).
    scores_part_kernel<<<dim3(32, 16, SD_SPLIT), 128, 0, stream>>>(E, G, scores);
}

// Round 12
// 171.656 us; speedup vs baseline: 2.9962x; 1.1360x over previous
//
#include <hip/hip_runtime.h>

#define B_SZ   512
#define VFD    4096
#define HIDD   2048
#define EMBD   300
#define NLAB   2000
#define NPAD   320

#define G1_SPLIT 4          // gemm1 k-chunks: K=4096 -> 1024 each, 512 blocks
#define G2_SPLIT 8          // gemm2 k-chunks: K=2048 -> 256 each, 320 blocks
#define SD_SPLIT 4          // scores d-quarters: 320 -> 80 dims each

typedef __attribute__((ext_vector_type(8))) short short8x;
typedef __attribute__((ext_vector_type(4))) float f32x4;
typedef __attribute__((ext_vector_type(8))) unsigned short ushort8;
typedef __attribute__((ext_vector_type(4))) unsigned short ushort4x;

typedef const __attribute__((address_space(1))) unsigned int* gas_t;
typedef __attribute__((address_space(3))) unsigned int* las_t;

__device__ inline unsigned short f2bf(float x) {
    unsigned u = __float_as_uint(x);
    u += 0x7FFF + ((u >> 16) & 1);          // round-to-nearest-even
    return (unsigned short)(u >> 16);
}

// ---------------------------------------------------------------------------
// Prep (4382 blocks):
//   [0,1024):     Xb = bf16(relu(vfs))
//   [1024,3072):  W1T[n][k] = bf16(W1[k][n])  (pair-packed transpose)
//   [3072,3232):  W2T[n][k] = bf16(W2[k][n]), n>=300 zero-padded
//   [3232,4232):  scores <- 0   (atomic target for scores_part)
//   [4232,4382):  E[m][n] <- b2[n]  (atomic target for gemm2)
// ---------------------------------------------------------------------------
__global__ __launch_bounds__(256) void prep_kernel(
    const float* __restrict__ vfs, unsigned short* __restrict__ Xb,
    const float* __restrict__ W1, unsigned short* __restrict__ W1T,
    const float* __restrict__ W2, unsigned short* __restrict__ W2T,
    float* __restrict__ scores, const float* __restrict__ b2,
    float* __restrict__ E)
{
    __shared__ unsigned int Lds[64][34];
    const int tid = threadIdx.x;
    const int blk = blockIdx.x;

    if (blk < 1024) {
        const int i = (blk * 256 + tid) * 8;
        float4 a = *(const float4*)&vfs[i];
        float4 b = *(const float4*)&vfs[i + 4];
        ushort8 o;
        o[0] = f2bf(fmaxf(a.x, 0.f)); o[1] = f2bf(fmaxf(a.y, 0.f));
        o[2] = f2bf(fmaxf(a.z, 0.f)); o[3] = f2bf(fmaxf(a.w, 0.f));
        o[4] = f2bf(fmaxf(b.x, 0.f)); o[5] = f2bf(fmaxf(b.y, 0.f));
        o[6] = f2bf(fmaxf(b.z, 0.f)); o[7] = f2bf(fmaxf(b.w, 0.f));
        *(ushort8*)&Xb[i] = o;
        return;
    }
    if (blk >= 4232) {                      // E = b2 (row-major [512][300])
        const int j = ((blk - 4232) * 256 + tid) * 4;   // j%4==0, 300%4==0
        if (j < B_SZ * EMBD) {
            const int n = j % EMBD;
            *(float4*)&E[j] = *(const float4*)&b2[n];
        }
        return;
    }
    if (blk >= 3232) {                      // scores = 0
        const int i = ((blk - 3232) * 256 + tid) * 4;
        if (i < B_SZ * NLAB) {
            float4 z = {0.f, 0.f, 0.f, 0.f};
            *(float4*)&scores[i] = z;
        }
        return;
    }

    const float* in; unsigned short* out; int N, ldK, bx, by;
    if (blk < 3072) {                       // W1: K=4096, N=2048, tiles (32,64)
        const int b = blk - 1024;
        in = W1; out = W1T; N = HIDD; ldK = VFD; bx = b & 31; by = b >> 5;
    } else {                                // W2: K=2048, N=300->320, tiles (5,32)
        const int b = blk - 3072;
        in = W2; out = W2T; N = EMBD; ldK = HIDD; bx = b % 5; by = b / 5;
    }
    const int n0 = bx * 64, k0 = by * 64;

    #pragma unroll
    for (int i = 0; i < 2; ++i) {
        const int s = tid + 256 * i;
        const int kp = s >> 4, nq = s & 15;
        const int n = n0 + nq * 4;
        float4 v0 = {0.f,0.f,0.f,0.f}, v1 = {0.f,0.f,0.f,0.f};
        if (n < N) {
            v0 = *(const float4*)&in[(size_t)(k0 + 2 * kp)     * N + n];
            v1 = *(const float4*)&in[(size_t)(k0 + 2 * kp + 1) * N + n];
        }
        Lds[nq*4+0][kp] = (unsigned)f2bf(v0.x) | ((unsigned)f2bf(v1.x) << 16);
        Lds[nq*4+1][kp] = (unsigned)f2bf(v0.y) | ((unsigned)f2bf(v1.y) << 16);
        Lds[nq*4+2][kp] = (unsigned)f2bf(v0.z) | ((unsigned)f2bf(v1.z) << 16);
        Lds[nq*4+3][kp] = (unsigned)f2bf(v0.w) | ((unsigned)f2bf(v1.w) << 16);
    }
    __syncthreads();

    #pragma unroll
    for (int i = 0; i < 2; ++i) {
        const int c = tid + 256 * i;
        const int n = c >> 3, oct = c & 7;
        uint2 lo = *(uint2*)&Lds[n][oct * 4];
        uint2 hi = *(uint2*)&Lds[n][oct * 4 + 2];
        uint4 v = make_uint4(lo.x, lo.y, hi.x, hi.y);
        *(uint4*)&out[(size_t)(n0 + n) * ldK + k0 + oct * 8] = v;
    }
}

// ---------------------------------------------------------------------------
// GEMM1 (r8-proven): Hpart[z][512][2048] = Xb @ W1T^T over k-chunk z.
// Block 64m x 128n, BK=64, split-K 4 -> grid (16,8,4) = 512 blocks = 2/CU.
// 4 waves, wave = 32m x 64n. LDS dbuf 48 KB.
// ---------------------------------------------------------------------------
__global__ __launch_bounds__(256) void gemm1_kernel(
    const unsigned short* __restrict__ A,
    const unsigned short* __restrict__ Bt,
    float* __restrict__ Cpart)
{
    __shared__ unsigned short As[2][4096];   // 8 oct x 64 rows
    __shared__ unsigned short Bs[2][8192];   // 8 oct x 128 rows

    const int tid = threadIdx.x;
    const int m0 = blockIdx.y * 64, n0 = blockIdx.x * 128;
    const int kbase = blockIdx.z * (VFD / G1_SPLIT);     // 1024

    const unsigned short* ga = A + (size_t)(m0 + (tid & 63)) * VFD + kbase + (tid >> 6) * 8;
    const unsigned short* gb = Bt + (size_t)(n0 + (tid & 127)) * VFD + kbase + (tid >> 7) * 8;

    const int lane = tid & 63;
    const int wave = tid >> 6;
    const int wm = (wave & 1) * 32;
    const int wn = (wave >> 1) * 64;
    const int q = lane >> 4, l15 = lane & 15;

    f32x4 acc[2][4];
    #pragma unroll
    for (int r = 0; r < 2; ++r)
        #pragma unroll
        for (int c = 0; c < 4; ++c) acc[r][c] = (f32x4){0.f,0.f,0.f,0.f};

    #pragma unroll
    for (int i = 0; i < 2; ++i)
        __builtin_amdgcn_global_load_lds((gas_t)(const void*)(ga + i * 32),
                                         (las_t)(void*)&As[0][(tid + 256 * i) * 8], 16, 0, 0);
    #pragma unroll
    for (int i = 0; i < 4; ++i)
        __builtin_amdgcn_global_load_lds((gas_t)(const void*)(gb + i * 16),
                                         (las_t)(void*)&Bs[0][(tid + 256 * i) * 8], 16, 0, 0);

    const int iters = (VFD / G1_SPLIT) / 64;             // 16
    for (int t = 0; t < iters; ++t) {
        const int cur = t & 1, nxt = cur ^ 1;
        __syncthreads();            // vmcnt drain: tile t present; buf[nxt] free

        if (t + 1 < iters) {
            const int ko = (t + 1) * 64;
            #pragma unroll
            for (int i = 0; i < 2; ++i)
                __builtin_amdgcn_global_load_lds((gas_t)(const void*)(ga + ko + i * 32),
                                                 (las_t)(void*)&As[nxt][(tid + 256 * i) * 8], 16, 0, 0);
            #pragma unroll
            for (int i = 0; i < 4; ++i)
                __builtin_amdgcn_global_load_lds((gas_t)(const void*)(gb + ko + i * 16),
                                                 (las_t)(void*)&Bs[nxt][(tid + 256 * i) * 8], 16, 0, 0);
        }

        #pragma unroll
        for (int kk = 0; kk < 2; ++kk) {
            const int oct = kk * 4 + q;
            short8x a0 = *(short8x*)&As[cur][(oct * 64 + wm +      l15) * 8];
            short8x a1 = *(short8x*)&As[cur][(oct * 64 + wm + 16 + l15) * 8];
            #pragma unroll
            for (int c = 0; c < 4; ++c) {
                short8x b = *(short8x*)&Bs[cur][(oct * 128 + wn + c * 16 + l15) * 8];
                acc[0][c] = __builtin_amdgcn_mfma_f32_16x16x32_bf16(a0, b, acc[0][c], 0, 0, 0);
                acc[1][c] = __builtin_amdgcn_mfma_f32_16x16x32_bf16(a1, b, acc[1][c], 0, 0, 0);
            }
        }
    }

    float* Cz = Cpart + (size_t)blockIdx.z * B_SZ * HIDD;
    #pragma unroll
    for (int r = 0; r < 2; ++r)
        #pragma unroll
        for (int g = 0; g < 4; ++g) {
            const int rr = m0 + wm + r * 16 + q * 4 + g;
            #pragma unroll
            for (int c = 0; c < 4; ++c)
                Cz[(size_t)rr * HIDD + n0 + wn + c * 16 + l15] = acc[r][c][g];
        }
}

// ---------------------------------------------------------------------------
// Hb = bf16(relu(sum_z Hpart[z] + b1)), 4 elems/thread. Grid 1024.
// ---------------------------------------------------------------------------
__global__ __launch_bounds__(256) void reduce_h_kernel(
    const float* __restrict__ Hpart, const float* __restrict__ b1,
    unsigned short* __restrict__ Hb)
{
    const int i = (blockIdx.x * 256 + threadIdx.x) * 4;
    const int col = i & (HIDD - 1);
    float4 s = *(const float4*)&b1[col];
    #pragma unroll
    for (int z = 0; z < G1_SPLIT; ++z) {
        float4 p = *(const float4*)&Hpart[(size_t)z * B_SZ * HIDD + i];
        s.x += p.x; s.y += p.y; s.z += p.z; s.w += p.w;
    }
    ushort4x o;
    o[0] = f2bf(fmaxf(s.x, 0.f));
    o[1] = f2bf(fmaxf(s.y, 0.f));
    o[2] = f2bf(fmaxf(s.z, 0.f));
    o[3] = f2bf(fmaxf(s.w, 0.f));
    *(ushort4x*)&Hb[i] = o;
}

// ---------------------------------------------------------------------------
// GEMM2 (split-K, atomic): E[m][n] += (Hb @ W2T^T chunk z), E pre-init = b2.
// Tile 64m x 64n, BK=64 (4 iters), grid (5, 8, 8) = 320 blocks.
// ---------------------------------------------------------------------------
__global__ __launch_bounds__(256) void gemm2_kernel(
    const unsigned short* __restrict__ A,
    const unsigned short* __restrict__ Bt,
    float* __restrict__ E)
{
    __shared__ unsigned short As[2][4096];
    __shared__ unsigned short Bs[2][4096];

    const int tid = threadIdx.x;
    const int m0 = blockIdx.y * 64, n0 = blockIdx.x * 64;
    const int kbase = blockIdx.z * (HIDD / G2_SPLIT);

    const unsigned short* ga = A  + (size_t)(m0 + (tid & 63)) * HIDD + kbase + (tid >> 6) * 8;
    const unsigned short* gb = Bt + (size_t)(n0 + (tid & 63)) * HIDD + kbase + (tid >> 6) * 8;

    const int lane = tid & 63;
    const int wave = tid >> 6;
    const int wm = (wave & 1) * 32;
    const int wn = (wave >> 1) * 32;
    const int q = lane >> 4, l15 = lane & 15;

    f32x4 acc00 = {0.f,0.f,0.f,0.f}, acc01 = {0.f,0.f,0.f,0.f};
    f32x4 acc10 = {0.f,0.f,0.f,0.f}, acc11 = {0.f,0.f,0.f,0.f};

    #pragma unroll
    for (int i = 0; i < 2; ++i) {
        __builtin_amdgcn_global_load_lds((gas_t)(const void*)(ga + i * 32),
                                         (las_t)(void*)&As[0][(tid + 256 * i) * 8], 16, 0, 0);
        __builtin_amdgcn_global_load_lds((gas_t)(const void*)(gb + i * 32),
                                         (las_t)(void*)&Bs[0][(tid + 256 * i) * 8], 16, 0, 0);
    }

    const int iters = (HIDD / G2_SPLIT) / 64;            // 4
    for (int t = 0; t < iters; ++t) {
        const int cur = t & 1, nxt = cur ^ 1;
        __syncthreads();

        if (t + 1 < iters) {
            const int ko = (t + 1) * 64;
            #pragma unroll
            for (int i = 0; i < 2; ++i) {
                __builtin_amdgcn_global_load_lds((gas_t)(const void*)(ga + ko + i * 32),
                                                 (las_t)(void*)&As[nxt][(tid + 256 * i) * 8], 16, 0, 0);
                __builtin_amdgcn_global_load_lds((gas_t)(const void*)(gb + ko + i * 32),
                                                 (las_t)(void*)&Bs[nxt][(tid + 256 * i) * 8], 16, 0, 0);
            }
        }

        #pragma unroll
        for (int kk = 0; kk < 2; ++kk) {
            const int oct = kk * 4 + q;
            short8x a0 = *(short8x*)&As[cur][(oct * 64 + wm +      l15) * 8];
            short8x a1 = *(short8x*)&As[cur][(oct * 64 + wm + 16 + l15) * 8];
            short8x b0 = *(short8x*)&Bs[cur][(oct * 64 + wn +      l15) * 8];
            short8x b1 = *(short8x*)&Bs[cur][(oct * 64 + wn + 16 + l15) * 8];
            acc00 = __builtin_amdgcn_mfma_f32_16x16x32_bf16(a0, b0, acc00, 0, 0, 0);
            acc01 = __builtin_amdgcn_mfma_f32_16x16x32_bf16(a0, b1, acc01, 0, 0, 0);
            acc10 = __builtin_amdgcn_mfma_f32_16x16x32_bf16(a1, b0, acc10, 0, 0, 0);
            acc11 = __builtin_amdgcn_mfma_f32_16x16x32_bf16(a1, b1, acc11, 0, 0, 0);
        }
    }

    const int cc = n0 + wn + l15;
    #pragma unroll
    for (int r = 0; r < 4; ++r) {
        const int rr = m0 + wm + q * 4 + r;
        if (cc < EMBD)      atomicAdd(&E[(size_t)rr * EMBD + cc],        acc00[r]);
        if (cc + 16 < EMBD) atomicAdd(&E[(size_t)rr * EMBD + cc + 16],   acc01[r]);
        if (cc < EMBD)      atomicAdd(&E[(size_t)(rr + 16) * EMBD + cc], acc10[r]);
        if (cc + 16 < EMBD) atomicAdd(&E[(size_t)(rr + 16) * EMBD + cc + 16], acc11[r]);
    }
}

// ---------------------------------------------------------------------------
// Scores partials: atomicAdd(scores[b][n], -sum_{d in quarter} relu(E-G)^2).
// Tile 32 b x 64 n, 128 threads, thread = 4 rows x 4 labels.
// Grid (32, 16, SD_SPLIT) = 2048 blocks.
// ---------------------------------------------------------------------------
__global__ __launch_bounds__(128) void scores_part_kernel(
    const float* __restrict__ E, const float* __restrict__ G,
    float* __restrict__ scores)
{
    __shared__ float Gs[64][44];

    const int tid = threadIdx.x;
    const int tx = tid & 15, ty = tid >> 4;
    const int n0 = blockIdx.x * 64, b0 = blockIdx.y * 32;
    const int dbase = blockIdx.z * (NPAD / SD_SPLIT);

    float acc[4][4] = {};

    for (int dc = 0; dc < NPAD / SD_SPLIT; dc += 40) {
        const int d0 = dbase + dc;
        __syncthreads();
        #pragma unroll
        for (int i = 0; i < 5; ++i) {
            const int s = tid + 128 * i;
            const int row = s / 10, qd = (s - row * 10) * 4;
            const int d = d0 + qd;
            const int n = n0 + row;
            float4 v = {0.f, 0.f, 0.f, 0.f};
            if (n < NLAB && d < EMBD) v = *(const float4*)&G[(size_t)n * EMBD + d];
            *(float4*)&Gs[row][qd] = v;
        }
        __syncthreads();

        #pragma unroll 2
        for (int d = 0; d < 40; d += 4) {
            const int dd = d0 + d;
            float4 e[4];
            if (dd < EMBD) {
                #pragma unroll
                for (int r = 0; r < 4; ++r)
                    e[r] = *(const float4*)&E[(size_t)(b0 + ty * 4 + r) * EMBD + dd];
            } else {
                #pragma unroll
                for (int r = 0; r < 4; ++r) e[r] = make_float4(0.f, 0.f, 0.f, 0.f);
            }
            #pragma unroll
            for (int c = 0; c < 4; ++c) {
                float4 g = *(float4*)&Gs[tx + 16 * c][d];
                #pragma unroll
                for (int r = 0; r < 4; ++r) {
                    float t;
                    t = fmaxf(e[r].x - g.x, 0.f); acc[r][c] += t * t;
                    t = fmaxf(e[r].y - g.y, 0.f); acc[r][c] += t * t;
                    t = fmaxf(e[r].z - g.z, 0.f); acc[r][c] += t * t;
                    t = fmaxf(e[r].w - g.w, 0.f); acc[r][c] += t * t;
                }
            }
        }
    }

    #pragma unroll
    for (int r = 0; r < 4; ++r) {
        const int b = b0 + ty * 4 + r;
        #pragma unroll
        for (int c = 0; c < 4; ++c) {
            const int n = n0 + tx + 16 * c;
            if (n < NLAB) atomicAdd(&scores[(size_t)b * NLAB + n], -acc[r][c]);
        }
    }
}

// ---------------------------------------------------------------------------
extern "C" void kernel_launch(void* const* d_in, const int* in_sizes, int n_in,
                              void* d_out, int out_size, void* d_ws, size_t ws_size,
                              hipStream_t stream)
{
    const float* vfs = (const float*)d_in[0];   // [512,4096]
    const float* W1  = (const float*)d_in[1];   // [4096,2048]
    const float* b1  = (const float*)d_in[2];   // [2048]
    const float* W2  = (const float*)d_in[3];   // [2048,300]
    const float* b2  = (const float*)d_in[4];   // [300]
    const float* G   = (const float*)d_in[5];   // [2000,300]

    float* out    = (float*)d_out;
    float* scores = out;                        // [512*2000]
    float* E      = out + (size_t)B_SZ * NLAB;  // [512*300]

    // workspace layout (bytes): ~39.3 MB used
    char* ws = (char*)d_ws;
    unsigned short* Xb  = (unsigned short*)(ws);             //  4 MB   [512][4096]
    unsigned short* W1T = (unsigned short*)(ws + 4194304);   // 16 MB   [2048][4096]
    unsigned short* W2T = (unsigned short*)(ws + 20971520);  // 1.25 MB [320][2048]
    unsigned short* Hb  = (unsigned short*)(ws + 22282240);  //  2 MB   [512][2048]
    float*          Hpart = (float*)(ws + 24379392);         // 16 MB   [4][512][2048]

    // prep: Xb (1024) + W1T (2048) + W2T (160) + scores=0 (1000) + E=b2 (150)
    prep_kernel<<<4382, 256, 0, stream>>>(vfs, Xb, W1, W1T, W2, W2T,
                                          scores, b2, E);

    // GEMM1: 64x128 tile, BK=64, split-K 4, grid (16,8,4) = 512 blocks (r8-proven)
    gemm1_kernel<<<dim3(16, 8, G1_SPLIT), 256, 0, stream>>>(Xb, W1T, Hpart);
    reduce_h_kernel<<<1024, 256, 0, stream>>>(Hpart, b1, Hb);

    // GEMM2: split-K 8, atomic into E (pre-init b2). Grid (5,8,8) = 320.
    gemm2_kernel<<<dim3(5, 8, G2_SPLIT), 256, 0, stream>>>(Hb, W2T, E);

    // Scores: 2048 blocks, atomic into scores (pre-init 0).
    scores_part_kernel<<<dim3(32, 16, SD_SPLIT), 128, 0, stream>>>(E, G, scores);
}